// Round 2
// baseline (940.108 us; speedup 1.0000x reference)
//
#include <hip/hip_runtime.h>
#include <hip/hip_bf16.h>
#include <stdint.h>

typedef __bf16 bf16;
typedef __bf16 bf16x8 __attribute__((ext_vector_type(8)));
typedef float  f32x4  __attribute__((ext_vector_type(4)));

#define T_TOK 16384
#define DDIM  1024
#define FDIM  4096
#define NEXP  8
#define MAXTILES 136   // sum_e ceil(counts[e]/128) <= 128+7; padded so grid%8==0

// ---------------- async global->LDS (width 16) ----------------
__device__ __forceinline__ void load_lds16(const bf16* g, bf16* l) {
  __builtin_amdgcn_global_load_lds(
      (const __attribute__((address_space(1))) void*)g,
      (__attribute__((address_space(3))) void*)l, 16, 0, 0);
}

// ---------------- router: fp32 logits + argmax (NO global atomics) ----------------
__global__ __launch_bounds__(256) void router_kernel(
    const float* __restrict__ x, const float* __restrict__ rw,
    const float* __restrict__ rb, int* __restrict__ idx) {
  int wave = threadIdx.x >> 6, lane = threadIdx.x & 63;
  int t = blockIdx.x * 4 + wave;
  const float* xr = x + (size_t)t * DDIM;
  float acc[NEXP];
#pragma unroll
  for (int e = 0; e < NEXP; e++) acc[e] = 0.f;
  for (int i = 0; i < DDIM / 64; i++) {
    int d = i * 64 + lane;
    float xv = xr[d];
    const float4* rwp = (const float4*)(rw + (size_t)d * NEXP);
    float4 r0 = rwp[0], r1 = rwp[1];
    acc[0] += xv * r0.x; acc[1] += xv * r0.y; acc[2] += xv * r0.z; acc[3] += xv * r0.w;
    acc[4] += xv * r1.x; acc[5] += xv * r1.y; acc[6] += xv * r1.z; acc[7] += xv * r1.w;
  }
#pragma unroll
  for (int e = 0; e < NEXP; e++)
#pragma unroll
    for (int off = 32; off > 0; off >>= 1)
      acc[e] += __shfl_down(acc[e], off, 64);
  if (lane == 0) {
    float best = acc[0] + rb[0]; int bi = 0;
#pragma unroll
    for (int e = 1; e < NEXP; e++) {
      float v = acc[e] + rb[e];
      if (v > best) { best = v; bi = e; }   // strict > == numpy first-max argmax
    }
    idx[t] = bi;
  }
}

// ---------------- histogram: LDS bins, 8 global atomics per block ----------------
__global__ __launch_bounds__(256) void hist_kernel(const int* __restrict__ idx,
                                                   int* __restrict__ counts) {
  __shared__ int h[NEXP];
  if (threadIdx.x < NEXP) h[threadIdx.x] = 0;
  __syncthreads();
  int t = blockIdx.x * 256 + threadIdx.x;
  atomicAdd(&h[idx[t]], 1);
  __syncthreads();
  if (threadIdx.x < NEXP) atomicAdd(&counts[threadIdx.x], h[threadIdx.x]);
}

// ------- offsets prefix-sum + lb loss + M-tile table (BM=128) -------
__global__ void offs_loss_kernel(const int* __restrict__ counts,
                                 int* __restrict__ offs, float* __restrict__ loss_out,
                                 int* __restrict__ tileE, int* __restrict__ tileM,
                                 int* __restrict__ nTiles) {
  int run = 0; float loss = 0.f; int nt = 0;
  for (int e = 0; e < NEXP; e++) {
    offs[e] = run; run += counts[e];
    int mt = (counts[e] + 127) >> 7;
    for (int m = 0; m < mt; m++) { tileE[nt] = e; tileM[nt] = m; nt++; }
    float u = (float)counts[e] / (float)T_TOK - 1.0f / (float)NEXP;
    loss += u * u;
  }
  *nTiles = nt;
  *loss_out = loss / (float)NEXP;
}

// ---------------- scatter: one cursor-atomic per (block, expert) ----------------
__global__ __launch_bounds__(256) void scatter_kernel(
    const int* __restrict__ idx, const int* __restrict__ offs,
    int* __restrict__ cursor, int* __restrict__ perm) {
  __shared__ int h[NEXP], base[NEXP];
  if (threadIdx.x < NEXP) h[threadIdx.x] = 0;
  __syncthreads();
  int t = blockIdx.x * 256 + threadIdx.x;
  int e = idx[t];
  int local = atomicAdd(&h[e], 1);        // LDS atomic
  __syncthreads();
  if (threadIdx.x < NEXP) base[threadIdx.x] = atomicAdd(&cursor[threadIdx.x], h[threadIdx.x]);
  __syncthreads();
  perm[offs[e] + base[e] + local] = t;
}

// ---------------- gather x rows (fp32) -> xg (bf16, expert order) ----------------
__global__ __launch_bounds__(256) void gather_kernel(
    const float* __restrict__ x, const int* __restrict__ perm, bf16* __restrict__ xg) {
  int wave = threadIdx.x >> 6, lane = threadIdx.x & 63;
  int p = blockIdx.x * 4 + wave;
  int t = perm[p];
  const float4* src = (const float4*)(x + (size_t)t * DDIM);
  bf16* dst = xg + (size_t)p * DDIM;
#pragma unroll
  for (int i = 0; i < 4; i++) {
    float4 v = src[i * 64 + lane];
    union { bf16 b[4]; uint64_t u; } cv;
    cv.b[0] = (bf16)v.x; cv.b[1] = (bf16)v.y; cv.b[2] = (bf16)v.z; cv.b[3] = (bf16)v.w;
    *(uint64_t*)(dst + (size_t)(i * 64 + lane) * 4) = cv.u;
  }
}

// ---------------- weight transpose+cast: [E][R][C] fp32 -> [E][C][R] bf16 ----------
__global__ __launch_bounds__(256) void transpose_cast_kernel(
    const float* __restrict__ src, bf16* __restrict__ dst, int R, int C) {
  __shared__ float tile[64][65];   // +1 pad: conflict-free transposed reads
  int e = blockIdx.z;
  src += (size_t)e * R * C;
  dst += (size_t)e * R * C;
  int tx = threadIdx.x & 63, ty = threadIdx.x >> 6;
  int bx = blockIdx.x, by = blockIdx.y;
#pragma unroll
  for (int i = 0; i < 64; i += 4)
    tile[ty + i][tx] = src[(size_t)(by * 64 + ty + i) * C + bx * 64 + tx];
  __syncthreads();
  int orow = threadIdx.x >> 4;          // 0..15
  int oc4  = (threadIdx.x & 15) * 4;    // 0..60
#pragma unroll
  for (int i = 0; i < 64; i += 16) {
    int r = orow + i;
    union { bf16 b[4]; ushort4 u; } v;
#pragma unroll
    for (int j = 0; j < 4; j++) v.b[j] = (bf16)tile[oc4 + j][r];
    *(ushort4*)&dst[(size_t)(bx * 64 + r) * R + by * 64 + oc4] = v.u;
  }
}

// =====================================================================
// Phased grouped GEMM: BM=128 x BN=256 x BK=64, 8 waves (wave tile 64x64),
// triple-buffered LDS (144 KiB) staged 2 K-tiles ahead, 2 phases/K-tile,
// 16 MFMA/phase, counted vmcnt(6), raw s_barrier, setprio around MFMA,
// T2 swizzle col ^= (row&7)*8 (inverse-swizzled global src, swizzled read).
// C[M,N] = A[M,K] * B[N,K]^T ; A rows expert-contiguous (permuted order).
// =====================================================================
template <int K, int N, bool LAYER1, int NWG>
__global__ __launch_bounds__(512, 2) void moe_gemm(
    const bf16* __restrict__ Aall, const bf16* __restrict__ Ball,
    const float* __restrict__ bias, bf16* __restrict__ hout, float* __restrict__ yout,
    const int* __restrict__ counts, const int* __restrict__ offs,
    const int* __restrict__ perm, const int* __restrict__ tileE,
    const int* __restrict__ tileM, const int* __restrict__ nTiles) {
  constexpr int NT = N / 256;
  constexpr int NK = K / 64;
  static_assert(NWG % 8 == 0, "grid must be divisible by 8 for XCD swizzle");

  // bijective XCD swizzle: XCD x (= bid&7) owns a contiguous logical chunk,
  // so all NT n-blocks of an m-tile share one XCD's L2 (A-tile resident).
  int bid = blockIdx.x;
  int logical = (bid & 7) * (NWG >> 3) + (bid >> 3);
  int tt = logical / NT, nn = logical % NT;
  if (tt >= *nTiles) return;
  int e = tileE[tt];
  int r0 = tileM[tt] << 7;
  int rows = counts[e];
  int off = offs[e];
  int n0 = nn << 8;
  const bf16* A = Aall + (size_t)off * K;
  const bf16* B = Ball + (size_t)e * (size_t)N * K;

  __shared__ bf16 sA[3][128][64];   // 48 KiB
  __shared__ bf16 sB[3][256][64];   // 96 KiB
  bf16* sAf = &sA[0][0][0];
  bf16* sBf = &sB[0][0][0];

  int tid = threadIdx.x;
  int lane = tid & 63, w = tid >> 6;
  int wm = w >> 2, wn = w & 3;                 // 2 x 4 wave grid

  // ---- staging addresses: linear LDS dest, inverse-swizzled global source ----
  // half-tile = 128 rows x 64 cols (16 KiB) = 2 x 16B loads/thread.
  // LDS granule (row, cg) holds global granule (row, cg ^ (row&7)).
  int srow = tid >> 3;                         // 0..63
  int scg  = tid & 7;
  int sswz = ((scg ^ (srow & 7)) << 3);        // element offset of source granule
  int ar0 = r0 + srow;       if (ar0 >= rows) ar0 = rows - 1;
  int ar1 = r0 + 64 + srow;  if (ar1 >= rows) ar1 = rows - 1;
  const bf16* gA0 = A + (size_t)ar0 * K + sswz;
  const bf16* gA1 = A + (size_t)ar1 * K + sswz;
  const bf16* gB0 = B + (size_t)(n0 + srow)       * K + sswz;
  const bf16* gB1 = B + (size_t)(n0 + 64 + srow)  * K + sswz;
  const bf16* gB2 = B + (size_t)(n0 + 128 + srow) * K + sswz;
  const bf16* gB3 = B + (size_t)(n0 + 192 + srow) * K + sswz;

#define STAGE_A(c, kt)  { load_lds16(gA0 + (kt) * 64, sAf + (c) * 8192 + tid * 8); \
                          load_lds16(gA1 + (kt) * 64, sAf + (c) * 8192 + 4096 + tid * 8); }
#define STAGE_B0(c, kt) { load_lds16(gB0 + (kt) * 64, sBf + (c) * 16384 + tid * 8); \
                          load_lds16(gB1 + (kt) * 64, sBf + (c) * 16384 + 4096 + tid * 8); }
#define STAGE_B1(c, kt) { load_lds16(gB2 + (kt) * 64, sBf + (c) * 16384 + 8192 + tid * 8); \
                          load_lds16(gB3 + (kt) * 64, sBf + (c) * 16384 + 12288 + tid * 8); }

  // ---- fragment read offsets (swizzled): (row&7) == (lane&7) for all frags ----
  int ln15 = lane & 15, l4 = lane >> 4;
  int am = wm * 64 + ln15;
  int bn = wn * 64 + ln15;
  int kq = l4 * 8;
  int fswz = (lane & 7) << 3;
  int ca0 = kq ^ fswz;                 // k-half 0 column (elements)
  int ca1 = (32 + kq) ^ fswz;          // k-half 1

  f32x4 acc[4][4] = {};

  // ---- prologue: K-tile 0 -> buf0, K-tile 1 -> buf1; wait oldest 6 (K0) ----
  STAGE_A(0, 0); STAGE_B0(0, 0); STAGE_B1(0, 0);
  STAGE_A(1, 1); STAGE_B0(1, 1); STAGE_B1(1, 1);
  asm volatile("s_waitcnt vmcnt(6)" ::: "memory");
  __builtin_amdgcn_s_barrier();

#pragma unroll 3
  for (int t = 0; t < NK; ++t) {
    int c  = t % 3;
    int s2 = (t + 2) % 3;
    int kt = (t + 2 < NK) ? (t + 2) : (NK - 1);   // clamp-stage keeps vmcnt counts uniform
    const bf16* lac = sAf + c * 8192;
    const bf16* lbc = sBf + c * 16384;
    bf16x8 a[4], b[4];

    // ---------- phase 1: k-half 0 ----------
#pragma unroll
    for (int mi = 0; mi < 4; mi++) a[mi] = *(const bf16x8*)(lac + (am + mi * 16) * 64 + ca0);
#pragma unroll
    for (int ni = 0; ni < 4; ni++) b[ni] = *(const bf16x8*)(lbc + (bn + ni * 16) * 64 + ca0);
    STAGE_A(s2, kt); STAGE_B0(s2, kt);
    __builtin_amdgcn_s_barrier();
    asm volatile("s_waitcnt lgkmcnt(0)" ::: "memory");
    __builtin_amdgcn_sched_barrier(0);
    __builtin_amdgcn_s_setprio(1);
#pragma unroll
    for (int mi = 0; mi < 4; mi++)
#pragma unroll
      for (int ni = 0; ni < 4; ni++)
        acc[mi][ni] = __builtin_amdgcn_mfma_f32_16x16x32_bf16(a[mi], b[ni], acc[mi][ni], 0, 0, 0);
    __builtin_amdgcn_s_setprio(0);
    __builtin_amdgcn_s_barrier();

    // ---------- phase 2: k-half 1 ----------
#pragma unroll
    for (int mi = 0; mi < 4; mi++) a[mi] = *(const bf16x8*)(lac + (am + mi * 16) * 64 + ca1);
#pragma unroll
    for (int ni = 0; ni < 4; ni++) b[ni] = *(const bf16x8*)(lbc + (bn + ni * 16) * 64 + ca1);
    STAGE_B1(s2, kt);
    __builtin_amdgcn_s_barrier();
    asm volatile("s_waitcnt lgkmcnt(0)" ::: "memory");
    __builtin_amdgcn_sched_barrier(0);
    __builtin_amdgcn_s_setprio(1);
#pragma unroll
    for (int mi = 0; mi < 4; mi++)
#pragma unroll
      for (int ni = 0; ni < 4; ni++)
        acc[mi][ni] = __builtin_amdgcn_mfma_f32_16x16x32_bf16(a[mi], b[ni], acc[mi][ni], 0, 0, 0);
    __builtin_amdgcn_s_setprio(0);
    // counted wait, once per K-tile: forces K(t+1) landed (oldest 6),
    // leaves this iteration's 6 stage-loads (K(t+2)) in flight.
    asm volatile("s_waitcnt vmcnt(6)" ::: "memory");
    __builtin_amdgcn_s_barrier();
  }

  // hardening: drain tail stage-loads before epilogue / endpgm (no outstanding
  // LDS-destined writes when the workgroup retires and LDS is reallocated)
  asm volatile("s_waitcnt vmcnt(0)" ::: "memory");

  // ---- epilogue: C/D layout col=lane&15, row=(lane>>4)*4+reg [m89/m91-verified]
  // one wave covers 64 consecutive cols per row -> full 128B lines (no write amp)
  int cb = n0 + wn * 64 + ln15;
  int rb = r0 + wm * 64 + l4 * 4;
#pragma unroll
  for (int ni = 0; ni < 4; ni++) {
    int col = cb + ni * 16;
    float bv = bias[e * N + col];
#pragma unroll
    for (int mi = 0; mi < 4; mi++) {
#pragma unroll
      for (int r = 0; r < 4; r++) {
        int row = rb + mi * 16 + r;
        if (row < rows) {
          float v = acc[mi][ni][r] + bv;
          if (LAYER1) {
            v = v > 0.f ? v : 0.f;
            hout[(size_t)(off + row) * N + col] = (bf16)v;
          } else {
            yout[(size_t)perm[off + row] * N + col] = v;
          }
        }
      }
    }
  }
#undef STAGE_A
#undef STAGE_B0
#undef STAGE_B1
}

// ---------------- launch ----------------
extern "C" void kernel_launch(void* const* d_in, const int* in_sizes, int n_in,
                              void* d_out, int out_size, void* d_ws, size_t ws_size,
                              hipStream_t stream) {
  const float* x   = (const float*)d_in[0];
  const float* rw  = (const float*)d_in[1];
  const float* rb  = (const float*)d_in[2];
  const float* w1  = (const float*)d_in[3];
  const float* b1  = (const float*)d_in[4];
  const float* w2  = (const float*)d_in[5];
  const float* b2  = (const float*)d_in[6];
  float* out = (float*)d_out;

  char* ws = (char*)d_ws;
  int* counts = (int*)(ws);         // 8 ints
  int* cursor = (int*)(ws + 64);    // 8 ints
  int* offs   = (int*)(ws + 128);   // 8 ints
  int* nTiles = (int*)(ws + 192);   // 1 int
  int* tileE  = (int*)(ws + 256);   // MAXTILES ints
  int* tileM  = (int*)(ws + 1024);  // MAXTILES ints
  int* idx    = (int*)(ws + 4096);                       // T ints
  int* perm   = (int*)(ws + 4096 + 65536);               // T ints
  size_t base = 135168;
  bf16* xg  = (bf16*)(ws + base);                         // 32 MB  [T,D]
  bf16* h   = (bf16*)(ws + base + 33554432ull);           // 128 MB [T,F]
  bf16* w1t = (bf16*)(ws + base + 33554432ull + 134217728ull);              // 64 MB [E,F,D]
  bf16* w2t = (bf16*)(ws + base + 33554432ull + 134217728ull + 67108864ull);// 64 MB [E,D,F]

  hipMemsetAsync(ws, 0, 256, stream);  // counts/cursor/offs/nTiles
  router_kernel<<<T_TOK / 4, 256, 0, stream>>>(x, rw, rb, idx);
  hist_kernel<<<T_TOK / 256, 256, 0, stream>>>(idx, counts);
  offs_loss_kernel<<<1, 1, 0, stream>>>(counts, offs, out + 16777216, tileE, tileM, nTiles);
  scatter_kernel<<<T_TOK / 256, 256, 0, stream>>>(idx, offs, cursor, perm);
  gather_kernel<<<T_TOK / 4, 256, 0, stream>>>(x, perm, xg);
  transpose_cast_kernel<<<dim3(64, 16, 8), 256, 0, stream>>>(w1, w1t, 1024, 4096);
  transpose_cast_kernel<<<dim3(16, 64, 8), 256, 0, stream>>>(w2, w2t, 4096, 1024);
  // layer1: K=1024 (NK=16), N=4096 (NT=16): ~2048 real blocks -> ~8 rounds/CU
  moe_gemm<DDIM, FDIM, true,  MAXTILES * 16><<<MAXTILES * 16, 512, 0, stream>>>(
      xg, w1t, b1, h, nullptr, counts, offs, perm, tileE, tileM, nTiles);
  // layer2: K=4096 (NK=64), N=1024 (NT=4): ~512 real blocks -> 2 rounds/CU
  moe_gemm<FDIM, DDIM, false, MAXTILES * 4><<<MAXTILES * 4, 512, 0, stream>>>(
      h, w2t, b2, nullptr, out, counts, offs, perm, tileE, tileM, nTiles);
}